// Round 9
// baseline (182.515 us; speedup 1.0000x reference)
//
#include <hip/hip_runtime.h>

#define DIM 8192
#define NLAYERS 8
#define SIMT 512        // sim threads: 8 waves, 16 amps/thread
#define QFB 2048
#define QFT 256
#define QROWS 4

typedef float floatx4 __attribute__((ext_vector_type(4)));
typedef float f2 __attribute__((ext_vector_type(2)));

// swizzle: all LDS round patterns become even 4-way (b64 minimum) [GF(2)-verified]
__device__ __forceinline__ int swz(int i) { return i ^ ((i >> 4) & 15); }

// ---------------------------------------------------------------------------
// Kernel A: statevector sim, 1 block. R3-verified structure (ping-pong LDS,
// 3 barriers/layer, layouts C->A->B->C with CNOT fused into the last round).
// Complex rotations written as packed-f2 ops: a' = c2*a + shuf(p)*(s,-s)
// -> v_pk_mul_f32 + v_pk_fma_f32 (2 inst/amp vs 4 scalar).
// Also resets the quad kernel's last-block ticket counter (runs first).
// ---------------------------------------------------------------------------
__global__ __launch_bounds__(SIMT) void sim_kernel(const float* __restrict__ params,
                                                   float* __restrict__ outR,
                                                   float* __restrict__ outM,
                                                   unsigned* __restrict__ counter) {
    __shared__ f2 buf[2][DIM];   // 128 KiB ping-pong
    const int t = threadIdx.x;
    if (t == 0) *counter = 0u;   // reset ticket for quad's fused reduction

    f2 a[16];
#pragma unroll
    for (int l = 0; l < 16; ++l) a[l] = (f2){0.f, 0.f};
    if (t == 0) a[0] = (f2){1.f, 0.f};

    int pp = 0;  // ping-pong parity

    for (int layer = 0; layer < NLAYERS; ++layer) {
        const float* __restrict__ prx = params + layer * 26;
        const float* __restrict__ prz = prx + 13;

        float cb[13], sb[13];
#pragma unroll
        for (int p = 0; p < 13; ++p) __sincosf(0.5f * prx[12 - p], &sb[p], &cb[p]);

        // ---- RX group 0: i-bits 0..3 (register-local pairs) ----
#pragma unroll
        for (int k = 0; k < 4; ++k) {
            const f2 c2 = {cb[k], cb[k]};
            const f2 sg = {sb[k], -sb[k]};
#pragma unroll
            for (int l0 = 0; l0 < 16; ++l0) {
                if (!(l0 & (1 << k))) {
                    const int l1 = l0 | (1 << k);
                    const f2 a0 = a[l0], a1 = a[l1];
                    a[l0] = c2 * a0 + __builtin_shufflevector(a1, a1, 1, 0) * sg;
                    a[l1] = c2 * a1 + __builtin_shufflevector(a0, a0, 1, 0) * sg;
                }
            }
        }

        // ---- R1: canonical -> layout A (1 barrier, ping-pong) ----
        {
            f2* __restrict__ B = buf[pp]; pp ^= 1;
#pragma unroll
            for (int l = 0; l < 16; ++l) B[swz((t << 4) | l)] = a[l];
            __syncthreads();
#pragma unroll
            for (int l = 0; l < 16; ++l) a[l] = B[swz((t & 15) | (l << 4) | ((t >> 4) << 8))];
        }

        // ---- RX group 1: i-bits 4..7 ----
#pragma unroll
        for (int k = 0; k < 4; ++k) {
            const f2 c2 = {cb[4 + k], cb[4 + k]};
            const f2 sg = {sb[4 + k], -sb[4 + k]};
#pragma unroll
            for (int l0 = 0; l0 < 16; ++l0) {
                if (!(l0 & (1 << k))) {
                    const int l1 = l0 | (1 << k);
                    const f2 a0 = a[l0], a1 = a[l1];
                    a[l0] = c2 * a0 + __builtin_shufflevector(a1, a1, 1, 0) * sg;
                    a[l1] = c2 * a1 + __builtin_shufflevector(a0, a0, 1, 0) * sg;
                }
            }
        }

        // ---- R2: layout A -> layout B ----
        {
            f2* __restrict__ B = buf[pp]; pp ^= 1;
#pragma unroll
            for (int l = 0; l < 16; ++l) B[swz((t & 15) | (l << 4) | ((t >> 4) << 8))] = a[l];
            __syncthreads();
#pragma unroll
            for (int l = 0; l < 16; ++l)
                a[l] = B[swz(((t >> 1) & 255) | (l << 8) | ((t & 1) << 12))];
        }

        // ---- RX group 2: i-bits 8..11 ----
#pragma unroll
        for (int k = 0; k < 4; ++k) {
            const f2 c2 = {cb[8 + k], cb[8 + k]};
            const f2 sg = {sb[8 + k], -sb[8 + k]};
#pragma unroll
            for (int l0 = 0; l0 < 16; ++l0) {
                if (!(l0 & (1 << k))) {
                    const int l1 = l0 | (1 << k);
                    const f2 a0 = a[l0], a1 = a[l1];
                    a[l0] = c2 * a0 + __builtin_shufflevector(a1, a1, 1, 0) * sg;
                    a[l1] = c2 * a1 + __builtin_shufflevector(a0, a0, 1, 0) * sg;
                }
            }
        }

        // ---- RX on bit 12: lane bit 0 via shfl_xor ----
        {
            const f2 c2 = {cb[12], cb[12]};
            const f2 sg = {sb[12], -sb[12]};
#pragma unroll
            for (int l = 0; l < 16; ++l) {
                f2 o;
                o.x = __shfl_xor(a[l].x, 1);
                o.y = __shfl_xor(a[l].y, 1);
                a[l] = c2 * a[l] + __builtin_shufflevector(o, o, 1, 0) * sg;
            }
        }

        // ---- RZ diagonal (layout B): a *= e^{i*phi} ----
        float hz[13];
#pragma unroll
        for (int p = 0; p < 13; ++p) hz[p] = 0.5f * prz[12 - p];
        float phiT = 0.f;
#pragma unroll
        for (int p = 0; p < 8; ++p) phiT += (((t >> 1) >> p) & 1) ? hz[p] : -hz[p];
        phiT += (t & 1) ? hz[12] : -hz[12];
#pragma unroll
        for (int l = 0; l < 16; ++l) {
            float phi = phiT;
            phi += (l & 1) ? hz[8]  : -hz[8];
            phi += (l & 2) ? hz[9]  : -hz[9];
            phi += (l & 4) ? hz[10] : -hz[10];
            phi += (l & 8) ? hz[11] : -hz[11];
            float sp, cp;
            __sincosf(phi, &sp, &cp);
            const f2 c2 = {cp, cp};
            const f2 sg = {-sp, sp};
            a[l] = c2 * a[l] + __builtin_shufflevector(a[l], a[l], 1, 0) * sg;
        }

        // ---- R3: CNOT round, layout B -> canonical (inverse suffix-parity) ----
        {
            f2* __restrict__ B = buf[pp]; pp ^= 1;
#pragma unroll
            for (int l = 0; l < 16; ++l)
                B[swz(((t >> 1) & 255) | (l << 8) | ((t & 1) << 12))] = a[l];
            __syncthreads();
#pragma unroll
            for (int l = 0; l < 16; ++l) {
                const int c0 = (t << 4) | l;
                a[l] = B[swz(c0 ^ (c0 >> 1))];
            }
        }
    }

    // ---- write r, m (canonical, contiguous float4) ----
#pragma unroll
    for (int g = 0; g < 4; ++g) {
        const float4 rv = make_float4(a[4*g].x, a[4*g+1].x, a[4*g+2].x, a[4*g+3].x);
        const float4 mv = make_float4(a[4*g].y, a[4*g+1].y, a[4*g+2].y, a[4*g+3].y);
        ((float4*)outR)[(t << 2) + g] = rv;
        ((float4*)outM)[(t << 2) + g] = mv;
    }
}

// ---------------------------------------------------------------------------
// Kernel B: partials = r^T O r + m^T O m, one NT streaming pass over O
// (HBM-bound floor ~42 us; L3 read BW ~= HBM BW so caching can't beat it).
// Final reduction fused via deterministic last-block ticket: integer atomic,
// fixed summation order -> bitwise-deterministic output.
// ---------------------------------------------------------------------------
__global__ __launch_bounds__(QFT) void quad_kernel(const float* __restrict__ O,
                                                   const float* __restrict__ R,
                                                   const float* __restrict__ M,
                                                   float* __restrict__ partials,
                                                   unsigned* __restrict__ counter,
                                                   float* __restrict__ out) {
    const int bi = blockIdx.x;
    const int t  = threadIdx.x;
    const float4* __restrict__ R4 = (const float4*)R;
    const float4* __restrict__ M4 = (const float4*)M;

    float acc = 0.f;
#pragma unroll
    for (int rr = 0; rr < QROWS; ++rr) {
        const int i = bi * QROWS + rr;
        const float ri = R[i];
        const float mi = M[i];
        const floatx4* __restrict__ Or = (const floatx4*)(O + (size_t)i * DIM);
#pragma unroll
        for (int it = 0; it < DIM / 4 / QFT; ++it) {   // 8 iterations
            const int j4 = t + it * QFT;
            const floatx4 o = __builtin_nontemporal_load(&Or[j4]);
            const float4 rj = R4[j4];
            const float4 mj = M4[j4];
            acc = fmaf(o.x, fmaf(ri, rj.x, mi * mj.x), acc);
            acc = fmaf(o.y, fmaf(ri, rj.y, mi * mj.y), acc);
            acc = fmaf(o.z, fmaf(ri, rj.z, mi * mj.z), acc);
            acc = fmaf(o.w, fmaf(ri, rj.w, mi * mj.w), acc);
        }
    }

    // block reduction: wave shuffle then LDS across the 4 waves
#pragma unroll
    for (int off = 32; off > 0; off >>= 1) acc += __shfl_down(acc, off);
    __shared__ float wsum[QFT / 64];
    __shared__ unsigned lastFlag;
    const int lane = t & 63, w = t >> 6;
    if (lane == 0) wsum[w] = acc;
    __syncthreads();
    if (t == 0) {
        float s = 0.f;
#pragma unroll
        for (int k = 0; k < QFT / 64; ++k) s += wsum[k];
        partials[bi] = s;
        __threadfence();   // publish partials before taking a ticket
        lastFlag = (atomicAdd(counter, 1u) == (unsigned)(QFB - 1));
    }
    __syncthreads();

    // last block sums all partials in fixed order (deterministic)
    if (lastFlag) {
        float acc2 = 0.f;
#pragma unroll
        for (int k = 0; k < QFB / QFT; ++k)
            acc2 += __hip_atomic_load(&partials[t + k * QFT],
                                      __ATOMIC_RELAXED, __HIP_MEMORY_SCOPE_AGENT);
#pragma unroll
        for (int off = 32; off > 0; off >>= 1) acc2 += __shfl_down(acc2, off);
        __syncthreads();
        if (lane == 0) wsum[w] = acc2;
        __syncthreads();
        if (t == 0) out[0] = wsum[0] + wsum[1] + wsum[2] + wsum[3];
    }
}

extern "C" void kernel_launch(void* const* d_in, const int* in_sizes, int n_in,
                              void* d_out, int out_size, void* d_ws, size_t ws_size,
                              hipStream_t stream) {
    const float* params = (const float*)d_in[0];   // 208 fp32
    const float* O      = (const float*)d_in[1];   // 8192*8192 fp32
    float* out = (float*)d_out;

    float*    R        = (float*)d_ws;
    float*    M        = R + DIM;
    float*    partials = M + DIM;
    unsigned* counter  = (unsigned*)(partials + QFB);

    sim_kernel<<<1, SIMT, 0, stream>>>(params, R, M, counter);
    quad_kernel<<<QFB, QFT, 0, stream>>>(O, R, M, partials, counter, out);
}

// Round 10
// 82.152 us; speedup vs baseline: 2.2217x; 2.2217x over previous
//
#include <hip/hip_runtime.h>

#define DIM 8192
#define NLAYERS 8
#define SIMT 512        // sim threads: 8 waves, 16 amps/thread
#define QFB 2048
#define QFT 256
#define ROWS_PER_BLOCK 4

typedef float floatx4 __attribute__((ext_vector_type(4)));
typedef float f2 __attribute__((ext_vector_type(2)));

// swizzle: all LDS round patterns become even 4-way (b64 minimum) [GF(2)-verified]
__device__ __forceinline__ int swz(int i) { return i ^ ((i >> 4) & 15); }

// ---------------------------------------------------------------------------
// Kernel 1: statevector sim, single block. R3-verified structure: ping-pong
// 2x64KB LDS, 3 barriers/layer, layouts C->A->B->C, CNOT fused into round 3.
// RX rotations in packed-f2 form: a' = c2*a + swap(partner)*(s,-s)
// (v_pk_mul_f32 + v_pk_fma_f32 -> half the scalar RX instruction count).
// RZ kept in the scalar R3-verified form. NO device-scope fences/atomics
// anywhere (round-9 lesson: they cost ~100us at high block counts).
// ---------------------------------------------------------------------------
__global__ __launch_bounds__(SIMT) void sim_kernel(const float* __restrict__ params,
                                                   float* __restrict__ outR,
                                                   float* __restrict__ outM) {
    __shared__ f2 buf[2][DIM];   // 128 KiB ping-pong
    const int t = threadIdx.x;

    f2 a[16];
#pragma unroll
    for (int l = 0; l < 16; ++l) a[l] = (f2){0.f, 0.f};
    if (t == 0) a[0] = (f2){1.f, 0.f};

    int pp = 0;  // ping-pong parity

    for (int layer = 0; layer < NLAYERS; ++layer) {
        const float* __restrict__ prx = params + layer * 26;
        const float* __restrict__ prz = prx + 13;

        float cb[13], sb[13];
#pragma unroll
        for (int p = 0; p < 13; ++p) __sincosf(0.5f * prx[12 - p], &sb[p], &cb[p]);

        // ---- RX group 0: i-bits 0..3 (register-local pairs) ----
#pragma unroll
        for (int k = 0; k < 4; ++k) {
            const f2 c2 = {cb[k], cb[k]};
            const f2 sg = {sb[k], -sb[k]};
#pragma unroll
            for (int l0 = 0; l0 < 16; ++l0) {
                if (!(l0 & (1 << k))) {
                    const int l1 = l0 | (1 << k);
                    const f2 a0 = a[l0], a1 = a[l1];
                    a[l0] = c2 * a0 + __builtin_shufflevector(a1, a1, 1, 0) * sg;
                    a[l1] = c2 * a1 + __builtin_shufflevector(a0, a0, 1, 0) * sg;
                }
            }
        }

        // ---- R1: canonical -> layout A (1 barrier, ping-pong) ----
        {
            f2* __restrict__ B = buf[pp]; pp ^= 1;
#pragma unroll
            for (int l = 0; l < 16; ++l) B[swz((t << 4) | l)] = a[l];
            __syncthreads();
#pragma unroll
            for (int l = 0; l < 16; ++l) a[l] = B[swz((t & 15) | (l << 4) | ((t >> 4) << 8))];
        }

        // ---- RX group 1: i-bits 4..7 ----
#pragma unroll
        for (int k = 0; k < 4; ++k) {
            const f2 c2 = {cb[4 + k], cb[4 + k]};
            const f2 sg = {sb[4 + k], -sb[4 + k]};
#pragma unroll
            for (int l0 = 0; l0 < 16; ++l0) {
                if (!(l0 & (1 << k))) {
                    const int l1 = l0 | (1 << k);
                    const f2 a0 = a[l0], a1 = a[l1];
                    a[l0] = c2 * a0 + __builtin_shufflevector(a1, a1, 1, 0) * sg;
                    a[l1] = c2 * a1 + __builtin_shufflevector(a0, a0, 1, 0) * sg;
                }
            }
        }

        // ---- R2: layout A -> layout B ----
        {
            f2* __restrict__ B = buf[pp]; pp ^= 1;
#pragma unroll
            for (int l = 0; l < 16; ++l) B[swz((t & 15) | (l << 4) | ((t >> 4) << 8))] = a[l];
            __syncthreads();
#pragma unroll
            for (int l = 0; l < 16; ++l)
                a[l] = B[swz(((t >> 1) & 255) | (l << 8) | ((t & 1) << 12))];
        }

        // ---- RX group 2: i-bits 8..11 ----
#pragma unroll
        for (int k = 0; k < 4; ++k) {
            const f2 c2 = {cb[8 + k], cb[8 + k]};
            const f2 sg = {sb[8 + k], -sb[8 + k]};
#pragma unroll
            for (int l0 = 0; l0 < 16; ++l0) {
                if (!(l0 & (1 << k))) {
                    const int l1 = l0 | (1 << k);
                    const f2 a0 = a[l0], a1 = a[l1];
                    a[l0] = c2 * a0 + __builtin_shufflevector(a1, a1, 1, 0) * sg;
                    a[l1] = c2 * a1 + __builtin_shufflevector(a0, a0, 1, 0) * sg;
                }
            }
        }

        // ---- RX on bit 12: lane bit 0 via shfl_xor ----
        {
            const f2 c2 = {cb[12], cb[12]};
            const f2 sg = {sb[12], -sb[12]};
#pragma unroll
            for (int l = 0; l < 16; ++l) {
                f2 o;
                o.x = __shfl_xor(a[l].x, 1);
                o.y = __shfl_xor(a[l].y, 1);
                a[l] = c2 * a[l] + __builtin_shufflevector(o, o, 1, 0) * sg;
            }
        }

        // ---- RZ diagonal (layout B), scalar R3-verified form ----
        float hz[13];
#pragma unroll
        for (int p = 0; p < 13; ++p) hz[p] = 0.5f * prz[12 - p];
        float phiT = 0.f;
#pragma unroll
        for (int p = 0; p < 8; ++p) phiT += (((t >> 1) >> p) & 1) ? hz[p] : -hz[p];
        phiT += (t & 1) ? hz[12] : -hz[12];
#pragma unroll
        for (int l = 0; l < 16; ++l) {
            float phi = phiT;
            phi += (l & 1) ? hz[8]  : -hz[8];
            phi += (l & 2) ? hz[9]  : -hz[9];
            phi += (l & 4) ? hz[10] : -hz[10];
            phi += (l & 8) ? hz[11] : -hz[11];
            float sp, cp;
            __sincosf(phi, &sp, &cp);
            a[l] = (f2){a[l].x * cp - a[l].y * sp, a[l].x * sp + a[l].y * cp};
        }

        // ---- R3: CNOT round, layout B -> canonical (inverse suffix-parity) ----
        {
            f2* __restrict__ B = buf[pp]; pp ^= 1;
#pragma unroll
            for (int l = 0; l < 16; ++l)
                B[swz(((t >> 1) & 255) | (l << 8) | ((t & 1) << 12))] = a[l];
            __syncthreads();
#pragma unroll
            for (int l = 0; l < 16; ++l) {
                const int c0 = (t << 4) | l;
                a[l] = B[swz(c0 ^ (c0 >> 1))];
            }
        }
    }

    // ---- write r, m (canonical, contiguous float4) ----
#pragma unroll
    for (int g = 0; g < 4; ++g) {
        const float4 rv = make_float4(a[4*g].x, a[4*g+1].x, a[4*g+2].x, a[4*g+3].x);
        const float4 mv = make_float4(a[4*g].y, a[4*g+1].y, a[4*g+2].y, a[4*g+3].y);
        ((float4*)outR)[(t << 2) + g] = rv;
        ((float4*)outM)[(t << 2) + g] = mv;
    }
}

// ---------------------------------------------------------------------------
// Kernel 2: partials = r^T O r + m^T O m — byte-identical to the proven R3
// quad (one NT streaming pass, ~95% of achievable HBM read BW).
// ---------------------------------------------------------------------------
__global__ __launch_bounds__(QFT) void quad_kernel(const float* __restrict__ O,
                                                   const float* __restrict__ R,
                                                   const float* __restrict__ M,
                                                   float* __restrict__ partials) {
    const int bi = blockIdx.x;
    const int t  = threadIdx.x;
    const float4* __restrict__ R4 = (const float4*)R;
    const float4* __restrict__ M4 = (const float4*)M;

    float acc = 0.f;
#pragma unroll
    for (int rr = 0; rr < ROWS_PER_BLOCK; ++rr) {
        const int i = bi * ROWS_PER_BLOCK + rr;
        const float ri = R[i];
        const float mi = M[i];
        const floatx4* __restrict__ Or = (const floatx4*)(O + (size_t)i * DIM);
#pragma unroll
        for (int it = 0; it < DIM / 4 / QFT; ++it) {   // 8 iterations
            const int j4 = t + it * QFT;
            const floatx4 o = __builtin_nontemporal_load(&Or[j4]);
            const float4 rj = R4[j4];
            const float4 mj = M4[j4];
            acc = fmaf(o.x, fmaf(ri, rj.x, mi * mj.x), acc);
            acc = fmaf(o.y, fmaf(ri, rj.y, mi * mj.y), acc);
            acc = fmaf(o.z, fmaf(ri, rj.z, mi * mj.z), acc);
            acc = fmaf(o.w, fmaf(ri, rj.w, mi * mj.w), acc);
        }
    }

#pragma unroll
    for (int off = 32; off > 0; off >>= 1) acc += __shfl_down(acc, off);
    __shared__ float wsum[QFT / 64];
    const int lane = t & 63, w = t >> 6;
    if (lane == 0) wsum[w] = acc;
    __syncthreads();
    if (t == 0) {
        float s = 0.f;
#pragma unroll
        for (int k = 0; k < QFT / 64; ++k) s += wsum[k];
        partials[bi] = s;
    }
}

__global__ __launch_bounds__(256) void reduce_kernel(const float* __restrict__ partials,
                                                     float* __restrict__ out) {
    const int t = threadIdx.x;
    float acc = 0.f;
#pragma unroll
    for (int k = 0; k < QFB / 256; ++k) acc += partials[t + k * 256];
#pragma unroll
    for (int off = 32; off > 0; off >>= 1) acc += __shfl_down(acc, off);
    __shared__ float wsum[4];
    const int lane = t & 63, w = t >> 6;
    if (lane == 0) wsum[w] = acc;
    __syncthreads();
    if (t == 0) out[0] = wsum[0] + wsum[1] + wsum[2] + wsum[3];
}

extern "C" void kernel_launch(void* const* d_in, const int* in_sizes, int n_in,
                              void* d_out, int out_size, void* d_ws, size_t ws_size,
                              hipStream_t stream) {
    const float* params = (const float*)d_in[0];   // 208 fp32
    const float* O      = (const float*)d_in[1];   // 8192*8192 fp32
    float* out = (float*)d_out;

    float* R        = (float*)d_ws;
    float* M        = R + DIM;
    float* partials = M + DIM;

    sim_kernel<<<1, SIMT, 0, stream>>>(params, R, M);
    quad_kernel<<<QFB, QFT, 0, stream>>>(O, R, M, partials);
    reduce_kernel<<<1, 256, 0, stream>>>(partials, out);
}

// Round 11
// 80.647 us; speedup vs baseline: 2.2631x; 1.0187x over previous
//
#include <hip/hip_runtime.h>

#define DIM 8192
#define NLAYERS 8
#define SIMT 1024       // sim threads: 16 waves (4/SIMD), 8 amps/thread
#define QFB 2048
#define QFT 256
#define ROWS_PER_BLOCK 4

typedef float floatx4 __attribute__((ext_vector_type(4)));
typedef float f2 __attribute__((ext_vector_type(2)));

// swizzle: verified even 4-way for all four round patterns below [GF(2)]
__device__ __forceinline__ int swz(int i) { return i ^ ((i >> 4) & 15); }

// ---------------------------------------------------------------------------
// Kernel 1: statevector sim, single block, 1024 threads (4 waves/SIMD for
// latency hiding). qubit q <-> bit p = 12-q. Thread t holds 8 amps.
// Layout cycle (all RX register-local or lane-shfl):
//   C: i = (t<<3)|l                       l = bits 0-2
//   A: i = (t&7)|(l<<3)|((t>>3)<<6)       l = bits 3-5
//   B: i = (t&63)|(l<<6)|((t>>6)<<9)      l = bits 6-8
//   D: i = ((t>>1)&511)|(l<<9)|((t&1)<<12)  l = bits 9-11, bit12 = lane bit 0
// Per layer: RX(0-2) -> T(C->A) -> RX(3-5) -> T(A->B) -> RX(6-8) -> T(B->D)
//         -> RX(9-11) -> RX(bit12, shfl_xor 1) -> RZ diag -> T(D->C)=CNOT.
// CNOT chain == suffix-parity perm; inverse gather i = j ^ (j>>1).
// Ping-pong 2x64KB LDS, ONE barrier per round (4/layer).
// RX in packed-f2 form (v_pk_mul/v_pk_fma), proven bit-exact in R10.
// ---------------------------------------------------------------------------
__global__ __launch_bounds__(SIMT) void sim_kernel(const float* __restrict__ params,
                                                   float* __restrict__ outR,
                                                   float* __restrict__ outM) {
    __shared__ f2 buf[2][DIM];   // 128 KiB ping-pong
    const int t = threadIdx.x;

    f2 a[8];
#pragma unroll
    for (int l = 0; l < 8; ++l) a[l] = (f2){0.f, 0.f};
    if (t == 0) a[0] = (f2){1.f, 0.f};

    int pp = 0;  // ping-pong parity

    for (int layer = 0; layer < NLAYERS; ++layer) {
        const float* __restrict__ prx = params + layer * 26;
        const float* __restrict__ prz = prx + 13;

        float cb[13], sb[13];
#pragma unroll
        for (int p = 0; p < 13; ++p) __sincosf(0.5f * prx[12 - p], &sb[p], &cb[p]);

        // ---- RX bits 0..2 (register-local, layout C) ----
#pragma unroll
        for (int k = 0; k < 3; ++k) {
            const f2 c2 = {cb[k], cb[k]};
            const f2 sg = {sb[k], -sb[k]};
#pragma unroll
            for (int l0 = 0; l0 < 8; ++l0) {
                if (!(l0 & (1 << k))) {
                    const int l1 = l0 | (1 << k);
                    const f2 a0 = a[l0], a1 = a[l1];
                    a[l0] = c2 * a0 + __builtin_shufflevector(a1, a1, 1, 0) * sg;
                    a[l1] = c2 * a1 + __builtin_shufflevector(a0, a0, 1, 0) * sg;
                }
            }
        }

        // ---- T1: C -> A ----
        {
            f2* __restrict__ B = buf[pp]; pp ^= 1;
#pragma unroll
            for (int l = 0; l < 8; ++l) B[swz((t << 3) | l)] = a[l];
            __syncthreads();
#pragma unroll
            for (int l = 0; l < 8; ++l)
                a[l] = B[swz((t & 7) | (l << 3) | ((t >> 3) << 6))];
        }

        // ---- RX bits 3..5 (layout A) ----
#pragma unroll
        for (int k = 0; k < 3; ++k) {
            const f2 c2 = {cb[3 + k], cb[3 + k]};
            const f2 sg = {sb[3 + k], -sb[3 + k]};
#pragma unroll
            for (int l0 = 0; l0 < 8; ++l0) {
                if (!(l0 & (1 << k))) {
                    const int l1 = l0 | (1 << k);
                    const f2 a0 = a[l0], a1 = a[l1];
                    a[l0] = c2 * a0 + __builtin_shufflevector(a1, a1, 1, 0) * sg;
                    a[l1] = c2 * a1 + __builtin_shufflevector(a0, a0, 1, 0) * sg;
                }
            }
        }

        // ---- T2: A -> B ----
        {
            f2* __restrict__ B = buf[pp]; pp ^= 1;
#pragma unroll
            for (int l = 0; l < 8; ++l)
                B[swz((t & 7) | (l << 3) | ((t >> 3) << 6))] = a[l];
            __syncthreads();
#pragma unroll
            for (int l = 0; l < 8; ++l)
                a[l] = B[swz((t & 63) | (l << 6) | ((t >> 6) << 9))];
        }

        // ---- RX bits 6..8 (layout B) ----
#pragma unroll
        for (int k = 0; k < 3; ++k) {
            const f2 c2 = {cb[6 + k], cb[6 + k]};
            const f2 sg = {sb[6 + k], -sb[6 + k]};
#pragma unroll
            for (int l0 = 0; l0 < 8; ++l0) {
                if (!(l0 & (1 << k))) {
                    const int l1 = l0 | (1 << k);
                    const f2 a0 = a[l0], a1 = a[l1];
                    a[l0] = c2 * a0 + __builtin_shufflevector(a1, a1, 1, 0) * sg;
                    a[l1] = c2 * a1 + __builtin_shufflevector(a0, a0, 1, 0) * sg;
                }
            }
        }

        // ---- T3: B -> D ----
        {
            f2* __restrict__ B = buf[pp]; pp ^= 1;
#pragma unroll
            for (int l = 0; l < 8; ++l)
                B[swz((t & 63) | (l << 6) | ((t >> 6) << 9))] = a[l];
            __syncthreads();
#pragma unroll
            for (int l = 0; l < 8; ++l)
                a[l] = B[swz(((t >> 1) & 511) | (l << 9) | ((t & 1) << 12))];
        }

        // ---- RX bits 9..11 (layout D) ----
#pragma unroll
        for (int k = 0; k < 3; ++k) {
            const f2 c2 = {cb[9 + k], cb[9 + k]};
            const f2 sg = {sb[9 + k], -sb[9 + k]};
#pragma unroll
            for (int l0 = 0; l0 < 8; ++l0) {
                if (!(l0 & (1 << k))) {
                    const int l1 = l0 | (1 << k);
                    const f2 a0 = a[l0], a1 = a[l1];
                    a[l0] = c2 * a0 + __builtin_shufflevector(a1, a1, 1, 0) * sg;
                    a[l1] = c2 * a1 + __builtin_shufflevector(a0, a0, 1, 0) * sg;
                }
            }
        }

        // ---- RX bit 12 (lane bit 0 in layout D): shfl_xor 1 ----
        {
            const f2 c2 = {cb[12], cb[12]};
            const f2 sg = {sb[12], -sb[12]};
#pragma unroll
            for (int l = 0; l < 8; ++l) {
                f2 o;
                o.x = __shfl_xor(a[l].x, 1);
                o.y = __shfl_xor(a[l].y, 1);
                a[l] = c2 * a[l] + __builtin_shufflevector(o, o, 1, 0) * sg;
            }
        }

        // ---- RZ diagonal (layout D): bits 0-8 = t>>1, 9-11 = l, 12 = t&1 ----
        float hz[13];
#pragma unroll
        for (int p = 0; p < 13; ++p) hz[p] = 0.5f * prz[12 - p];
        float phiT = 0.f;
#pragma unroll
        for (int p = 0; p < 9; ++p) phiT += (((t >> 1) >> p) & 1) ? hz[p] : -hz[p];
        phiT += (t & 1) ? hz[12] : -hz[12];
#pragma unroll
        for (int l = 0; l < 8; ++l) {
            float phi = phiT;
            phi += (l & 1) ? hz[9]  : -hz[9];
            phi += (l & 2) ? hz[10] : -hz[10];
            phi += (l & 4) ? hz[11] : -hz[11];
            float sp, cp;
            __sincosf(phi, &sp, &cp);
            a[l] = (f2){a[l].x * cp - a[l].y * sp, a[l].x * sp + a[l].y * cp};
        }

        // ---- T4: CNOT round, D -> canonical (inverse suffix-parity gather) ----
        {
            f2* __restrict__ B = buf[pp]; pp ^= 1;
#pragma unroll
            for (int l = 0; l < 8; ++l)
                B[swz(((t >> 1) & 511) | (l << 9) | ((t & 1) << 12))] = a[l];
            __syncthreads();
#pragma unroll
            for (int l = 0; l < 8; ++l) {
                const int c0 = (t << 3) | l;
                a[l] = B[swz(c0 ^ (c0 >> 1))];
            }
        }
    }

    // ---- write r, m (canonical: thread t owns amps [8t, 8t+8) ) ----
    {
        const float4 rv0 = make_float4(a[0].x, a[1].x, a[2].x, a[3].x);
        const float4 rv1 = make_float4(a[4].x, a[5].x, a[6].x, a[7].x);
        const float4 mv0 = make_float4(a[0].y, a[1].y, a[2].y, a[3].y);
        const float4 mv1 = make_float4(a[4].y, a[5].y, a[6].y, a[7].y);
        ((float4*)outR)[2 * t]     = rv0;
        ((float4*)outR)[2 * t + 1] = rv1;
        ((float4*)outM)[2 * t]     = mv0;
        ((float4*)outM)[2 * t + 1] = mv1;
    }
}

// ---------------------------------------------------------------------------
// Kernel 2: partials = r^T O r + m^T O m — byte-identical to the proven R10
// quad (one NT streaming pass, at the HBM/L3 read-BW floor).
// ---------------------------------------------------------------------------
__global__ __launch_bounds__(QFT) void quad_kernel(const float* __restrict__ O,
                                                   const float* __restrict__ R,
                                                   const float* __restrict__ M,
                                                   float* __restrict__ partials) {
    const int bi = blockIdx.x;
    const int t  = threadIdx.x;
    const float4* __restrict__ R4 = (const float4*)R;
    const float4* __restrict__ M4 = (const float4*)M;

    float acc = 0.f;
#pragma unroll
    for (int rr = 0; rr < ROWS_PER_BLOCK; ++rr) {
        const int i = bi * ROWS_PER_BLOCK + rr;
        const float ri = R[i];
        const float mi = M[i];
        const floatx4* __restrict__ Or = (const floatx4*)(O + (size_t)i * DIM);
#pragma unroll
        for (int it = 0; it < DIM / 4 / QFT; ++it) {   // 8 iterations
            const int j4 = t + it * QFT;
            const floatx4 o = __builtin_nontemporal_load(&Or[j4]);
            const float4 rj = R4[j4];
            const float4 mj = M4[j4];
            acc = fmaf(o.x, fmaf(ri, rj.x, mi * mj.x), acc);
            acc = fmaf(o.y, fmaf(ri, rj.y, mi * mj.y), acc);
            acc = fmaf(o.z, fmaf(ri, rj.z, mi * mj.z), acc);
            acc = fmaf(o.w, fmaf(ri, rj.w, mi * mj.w), acc);
        }
    }

#pragma unroll
    for (int off = 32; off > 0; off >>= 1) acc += __shfl_down(acc, off);
    __shared__ float wsum[QFT / 64];
    const int lane = t & 63, w = t >> 6;
    if (lane == 0) wsum[w] = acc;
    __syncthreads();
    if (t == 0) {
        float s = 0.f;
#pragma unroll
        for (int k = 0; k < QFT / 64; ++k) s += wsum[k];
        partials[bi] = s;
    }
}

__global__ __launch_bounds__(256) void reduce_kernel(const float* __restrict__ partials,
                                                     float* __restrict__ out) {
    const int t = threadIdx.x;
    float acc = 0.f;
#pragma unroll
    for (int k = 0; k < QFB / 256; ++k) acc += partials[t + k * 256];
#pragma unroll
    for (int off = 32; off > 0; off >>= 1) acc += __shfl_down(acc, off);
    __shared__ float wsum[4];
    const int lane = t & 63, w = t >> 6;
    if (lane == 0) wsum[w] = acc;
    __syncthreads();
    if (t == 0) out[0] = wsum[0] + wsum[1] + wsum[2] + wsum[3];
}

extern "C" void kernel_launch(void* const* d_in, const int* in_sizes, int n_in,
                              void* d_out, int out_size, void* d_ws, size_t ws_size,
                              hipStream_t stream) {
    const float* params = (const float*)d_in[0];   // 208 fp32
    const float* O      = (const float*)d_in[1];   // 8192*8192 fp32
    float* out = (float*)d_out;

    float* R        = (float*)d_ws;
    float* M        = R + DIM;
    float* partials = M + DIM;

    sim_kernel<<<1, SIMT, 0, stream>>>(params, R, M);
    quad_kernel<<<QFB, QFT, 0, stream>>>(O, R, M, partials);
    reduce_kernel<<<1, 256, 0, stream>>>(partials, out);
}